// Round 5
// baseline (218.295 us; speedup 1.0000x reference)
//
#include <hip/hip_runtime.h>
#include <math.h>

#define N_NODES 50000
#define D       64
#define N_EDGES 800000
#define N_HEAD  4

typedef unsigned short ushort_t;

// bf16 <-> fp32 bit helpers (RNE on pack)
__device__ __forceinline__ float bf_lo(unsigned u) {
    return __uint_as_float(u << 16);
}
__device__ __forceinline__ float bf_hi(unsigned u) {
    return __uint_as_float(u & 0xffff0000u);
}
__device__ __forceinline__ ushort_t f2bf(float f) {
    unsigned u = __float_as_uint(f);
    u += 0x7fffu + ((u >> 16) & 1u);   // round-to-nearest-even
    return (ushort_t)(u >> 16);
}

// ---------------------------------------------------------------------------
// row_ptr[r] = lower_bound(edge_row, r)  for r in [0, N_NODES], edge_row sorted
// ---------------------------------------------------------------------------
__global__ void rowptr_kernel(const int* __restrict__ edge_row,
                              int* __restrict__ row_ptr) {
    int r = blockIdx.x * blockDim.x + threadIdx.x;
    if (r > N_NODES) return;
    int lo = 0, hi = N_EDGES;
    while (lo < hi) {
        int mid = (lo + hi) >> 1;
        if (edge_row[mid] < r) lo = mid + 1; else hi = mid;
    }
    row_ptr[r] = lo;
}

// ---------------------------------------------------------------------------
// cv[e] = (edge_col[e], bits(edge_val[e])) — one 8B load per edge later.
// ---------------------------------------------------------------------------
__global__ void pair_kernel(const int* __restrict__ edge_col,
                            const float* __restrict__ edge_val,
                            int2* __restrict__ cv) {
    int e = blockIdx.x * blockDim.x + threadIdx.x;
    if (e < N_EDGES) cv[e] = make_int2(edge_col[e], __float_as_int(edge_val[e]));
}

// ---------------------------------------------------------------------------
// t[n][j] = bf16( elu( sum_k in[n][k] * W[j][k] + b[j] ) )
// lane j holds W[j][0..63] in 64 VGPRs; row data via wave-uniform scalar loads.
// ---------------------------------------------------------------------------
__global__ __launch_bounds__(256) void linear_elu_kernel(
        const float* __restrict__ in,
        const float* __restrict__ W,   // [64][64] row-major, W[j][k]
        const float* __restrict__ b,   // [64]
        const int*  __restrict__ et,   // mask if et[n]==0 (head 0 only)
        ushort_t* __restrict__ t,      // bf16 out
        int head0) {
    const int lane = threadIdx.x & 63;
    const int wid  = (blockIdx.x * blockDim.x + threadIdx.x) >> 6;
    const int nwav = (gridDim.x * blockDim.x) >> 6;

    float4 w4[16];
    {
        const float4* wp = (const float4*)(W + lane * D);
        #pragma unroll
        for (int i = 0; i < 16; ++i) w4[i] = wp[i];
    }
    const float* w = (const float*)w4;
    const float bj = b[lane];

    for (int row0 = wid; row0 < N_NODES; row0 += nwav) {
        const int row = __builtin_amdgcn_readfirstlane(row0);
        float acc = bj;
        if (!(head0 && et[row] == 0)) {
            const float* rp = in + (size_t)row * D;
            #pragma unroll
            for (int k = 0; k < D; ++k)
                acc = fmaf(rp[k], w[k], acc);
        }
        const float e = (acc > 0.f) ? acc : expm1f(acc);
        t[(size_t)row * D + lane] = f2bf(e);
    }
}

// ---------------------------------------------------------------------------
// SpMM: h[r][:] = sum_{e in row r} val[e] * t[col[e]][:]   (t is bf16)
// One wave per row; 4 groups of 16 lanes. A single masked iteration covers
// 32 edges (8 slots x 4 groups): one metadata round (8x int2, coalesced),
// then 8 independent dwordx2 gathers in flight. Poisson(16) degrees => ~all
// rows finish in ONE iteration = 2 dependent memory rounds total.
// Masked slots clamp to edge e1-1 with v=0 (exact no-op in fp32 fma).
// ---------------------------------------------------------------------------
__global__ __launch_bounds__(256) void spmm_kernel(
        const ushort_t* __restrict__ t,   // bf16 [N][64]
        const int2*  __restrict__ cv,     // (col, val-bits) [E]
        const int*   __restrict__ row_ptr,
        float* __restrict__ h,
        float* __restrict__ out,
        int first_head, int write_h) {
    const int lane = threadIdx.x & 63;
    const int g    = lane >> 4;    // edge slot within quad
    const int l    = lane & 15;    // dim quad: dims [4l, 4l+4)
    int row0 = (blockIdx.x * blockDim.x + threadIdx.x) >> 6;
    if (row0 >= N_NODES) return;
    const int row = __builtin_amdgcn_readfirstlane(row0);

    const int e0 = row_ptr[row];
    const int e1 = row_ptr[row + 1];
    float4 acc = {0.f, 0.f, 0.f, 0.f};

    for (int e = e0; e < e1; e += 32) {
        int   c[8];
        float v[8];
        #pragma unroll
        for (int u = 0; u < 8; ++u) {
            const int  ce = e + 4 * u + g;
            const bool ok = ce < e1;
            const int2 p  = cv[ok ? ce : (e1 - 1)];
            c[u] = p.x;
            v[u] = ok ? __int_as_float(p.y) : 0.f;
        }
        uint2 r2[8];
        #pragma unroll
        for (int u = 0; u < 8; ++u)
            r2[u] = *(const uint2*)(t + (size_t)c[u] * D + l * 4);
        #pragma unroll
        for (int u = 0; u < 8; ++u) {
            acc.x = fmaf(v[u], bf_lo(r2[u].x), acc.x);
            acc.y = fmaf(v[u], bf_hi(r2[u].x), acc.y);
            acc.z = fmaf(v[u], bf_lo(r2[u].y), acc.z);
            acc.w = fmaf(v[u], bf_hi(r2[u].y), acc.w);
        }
    }

    // reduce across the 4 groups (lanes differing in bits 4,5)
    #pragma unroll
    for (int off = 16; off < 64; off <<= 1) {
        acc.x += __shfl_xor(acc.x, off, 64);
        acc.y += __shfl_xor(acc.y, off, 64);
        acc.z += __shfl_xor(acc.z, off, 64);
        acc.w += __shfl_xor(acc.w, off, 64);
    }

    if (g == 0) {
        const size_t base = (size_t)row * D + (size_t)l * 4;
        if (write_h) *(float4*)(h + base) = acc;
        if (first_head) {
            *(float4*)(out + base) = acc;
        } else {
            float4 o = *(const float4*)(out + base);
            o.x += acc.x; o.y += acc.y; o.z += acc.z; o.w += acc.w;
            *(float4*)(out + base) = o;
        }
    }
}

// ---------------------------------------------------------------------------
extern "C" void kernel_launch(void* const* d_in, const int* in_sizes, int n_in,
                              void* d_out, int out_size, void* d_ws, size_t ws_size,
                              hipStream_t stream) {
    const float* x        = (const float*)d_in[0];  // [N, 64]
    const float* edge_val = (const float*)d_in[1];  // [E]
    const float* W        = (const float*)d_in[2];  // [4, 64, 64]
    const float* b        = (const float*)d_in[3];  // [4, 64]
    const int* edge_row   = (const int*)d_in[4];    // sorted
    const int* edge_col   = (const int*)d_in[5];
    const int* event_type = (const int*)d_in[6];    // [N] (int32 on device)
    float* out = (float*)d_out;

    ushort_t* t    = (ushort_t*)d_ws;                      // bf16 [N*64]  (6.4 MB)
    float* h       = (float*)(t + (size_t)N_NODES * D);    // fp32 [N*64]  (12.8 MB)
    int*   row_ptr = (int*)(h + (size_t)N_NODES * D);      // [N+1]
    int2*  cv      = (int2*)(row_ptr + (N_NODES + 2));     // [E] (8B each)

    rowptr_kernel<<<(N_NODES + 256) / 256, 256, 0, stream>>>(edge_row, row_ptr);
    pair_kernel<<<(N_EDGES + 255) / 256, 256, 0, stream>>>(edge_col, edge_val, cv);

    const float* cur = x;
    for (int i = 0; i < N_HEAD; ++i) {
        linear_elu_kernel<<<1024, 256, 0, stream>>>(
            cur, W + (size_t)i * D * D, b + (size_t)i * D,
            event_type, t, (i == 0) ? 1 : 0);
        spmm_kernel<<<(N_NODES * 64 + 255) / 256, 256, 0, stream>>>(
            t, cv, row_ptr, h, out,
            (i == 0) ? 1 : 0, (i < N_HEAD - 1) ? 1 : 0);
        cur = h;
    }
}